// Round 6
// baseline (290.580 us; speedup 1.0000x reference)
//
#include <hip/hip_runtime.h>
#include <stdint.h>

#define N_TOK  16384
#define EMB    512
#define NEMB   2048
#define NCHUNK 32            // 64 templates per chunk
#define CWIN   2.5e-4f       // ref-f32-grid + bf16 score-noise margin (passed R5)
#define WCAP   524288

typedef __attribute__((ext_vector_type(8))) short s16x8;
typedef __attribute__((ext_vector_type(4))) float f32x4;

__device__ __forceinline__ unsigned short f2bf(float f) {   // RNE f32 -> bf16
  unsigned u = __float_as_uint(f);
  u += 0x7fffu + ((u >> 16) & 1u);
  return (unsigned short)(u >> 16);
}

// numpy pairwise_sum emulation for sum(x*x) over 512 contiguous f32.
__device__ __forceinline__ float pairwise512_sq(const float* se, int lane) {
  int l = lane & 31;
  int b = l >> 3, j = l & 7;
  const float* base = se + b * 128 + j;
  float x = base[0];
  float r = __fmul_rn(x, x);
#pragma unroll
  for (int k = 1; k < 16; ++k) {
    float y = base[8 * k];
    r = __fadd_rn(r, __fmul_rn(y, y));
  }
  r = __fadd_rn(r, __shfl_xor(r, 1));
  r = __fadd_rn(r, __shfl_xor(r, 2));
  r = __fadd_rn(r, __shfl_xor(r, 4));
  r = __fadd_rn(r, __shfl_xor(r, 8));
  r = __fadd_rn(r, __shfl_xor(r, 16));
  return r;
}

// ---------- kernel 1: templat -> bf16 thi + numpy-exact t_sq ----------
__global__ void prep_t_kernel(const float* __restrict__ tmp,
                              unsigned short* __restrict__ thi, float* __restrict__ tsq) {
  __shared__ float se[EMB];
  int m = blockIdx.x, lane = threadIdx.x;                    // 64 lanes
  const float4* p = (const float4*)(tmp + (size_t)m * EMB) + lane * 2;
  float4 v0 = p[0], v1 = p[1];
  float f[8] = {v0.x, v0.y, v0.z, v0.w, v1.x, v1.y, v1.z, v1.w};
  unsigned h[8];
#pragma unroll
  for (int i = 0; i < 8; ++i) { h[i] = f2bf(f[i]); se[lane * 8 + i] = f[i]; }
  uint4 packed = { h[0] | (h[1] << 16), h[2] | (h[3] << 16),
                   h[4] | (h[5] << 16), h[6] | (h[7] << 16) };
  ((uint4*)(thi + (size_t)m * EMB))[lane] = packed;
  __syncthreads();
  float s = pairwise512_sq(se, lane);
  if (lane == 0) tsq[m] = s;
}

// ---------- kernel 1b: numpy-exact e_sq, one wave per token ----------
__global__ __launch_bounds__(256) void esq_kernel(const float* __restrict__ enc,
                                                  float* __restrict__ esq) {
  __shared__ float se[4][EMB];
  int wave = threadIdx.x >> 6, lane = threadIdx.x & 63;
  int token = blockIdx.x * 4 + wave;
  const float4* p = (const float4*)(enc + (size_t)token * EMB);
  ((float4*)se[wave])[lane]      = p[lane];
  ((float4*)se[wave])[lane + 64] = p[lane + 64];
  __syncthreads();
  float s = pairwise512_sq(se[wave], lane);
  if (lane == 0) esq[token] = s;
}

// ---------- kernel 2: m97-style 128x128 GEMM tile + fused argmin epilogue ----------
// grid 2048: tokb = bid>>4 (128 tokens), mb = bid&15 (128 templates). BK=64.
// Wave w: token-tiles (w>>1)*4+{0..3}, m-tiles (w&1)*4+{0..3} -> 64x64 output.
// Per K-chunk: B staged async (global_load_lds w=16), A staged f32->bf16 manually.
__global__ __launch_bounds__(256, 3) void score_kernel(
    const float* __restrict__ enc, const unsigned short* __restrict__ thi,
    const float* __restrict__ tsq,
    float* __restrict__ bestc, float* __restrict__ secondc, int* __restrict__ idxc) {
  __shared__ uint4 sA[1024];                    // 16 KB: [(tile*2+ks)*64 + lane]
  __shared__ uint4 sB[1024];                    // 16 KB
  const int tid = threadIdx.x, w = tid >> 6, lane = tid & 63;
  const int q = lane >> 4, r = lane & 15;
  const int tokb = (int)blockIdx.x >> 4;
  const int mb   = (int)blockIdx.x & 15;

  f32x4 acc[4][4];
#pragma unroll
  for (int ti = 0; ti < 4; ++ti)
#pragma unroll
    for (int j = 0; j < 4; ++j) acc[ti][j] = (f32x4){0.f, 0.f, 0.f, 0.f};

  for (int kb = 0; kb < 8; ++kb) {
    const int colb = kb * 64;
    // B: async global->LDS, fragment order (wave-uniform LDS base + lane*16)
#pragma unroll
    for (int n = 0; n < 4; ++n) {
      int p = w + n * 4, tile = p >> 1, ks = p & 1;
      const unsigned short* g =
          thi + (size_t)(mb * 128 + tile * 16 + r) * EMB + colb + ks * 32 + q * 8;
      __builtin_amdgcn_global_load_lds(
          (const __attribute__((address_space(1))) void*)g,
          (__attribute__((address_space(3))) void*)&sB[(tile * 2 + ks) * 64], 16, 0, 0);
    }
    // A: f32 load -> bf16 pack -> ds_write (lane-identity: conflict-free)
#pragma unroll
    for (int n = 0; n < 4; ++n) {
      int p = w + n * 4, tile = p >> 1, ks = p & 1;
      const float4* g = (const float4*)(enc +
          (size_t)(tokb * 128 + tile * 16 + r) * EMB + colb + ks * 32 + q * 8);
      float4 x = g[0], y = g[1];
      uint4 pk;
      pk.x = f2bf(x.x) | ((unsigned)f2bf(x.y) << 16);
      pk.y = f2bf(x.z) | ((unsigned)f2bf(x.w) << 16);
      pk.z = f2bf(y.x) | ((unsigned)f2bf(y.y) << 16);
      pk.w = f2bf(y.z) | ((unsigned)f2bf(y.w) << 16);
      sA[(tile * 2 + ks) * 64 + lane] = pk;
    }
    __syncthreads();
#pragma unroll
    for (int ks = 0; ks < 2; ++ks) {
      s16x8 af[4], bfr[4];
#pragma unroll
      for (int ti = 0; ti < 4; ++ti)
        af[ti] = ((const s16x8*)sA)[((((w >> 1) * 4 + ti) * 2 + ks) << 6) + lane];
#pragma unroll
      for (int j = 0; j < 4; ++j)
        bfr[j] = ((const s16x8*)sB)[((((w & 1) * 4 + j) * 2 + ks) << 6) + lane];
#pragma unroll
      for (int ti = 0; ti < 4; ++ti)
#pragma unroll
        for (int j = 0; j < 4; ++j)
          acc[ti][j] = __builtin_amdgcn_mfma_f32_16x16x32_bf16(af[ti], bfr[j],
                                                               acc[ti][j], 0, 0, 0);
    }
    __syncthreads();
  }

  // ---- single epilogue: scores, per-(token,chunk) best/second/idx ----
  // C/D layout: col(template) = r, row(token) = q*4 + i
  const int chunk = mb * 2 + (w & 1);
  float tq[4]; int mbase[4];
#pragma unroll
  for (int j = 0; j < 4; ++j) {
    mbase[j] = mb * 128 + ((w & 1) * 4 + j) * 16 + r;
    tq[j] = tsq[mbase[j]];
  }
#pragma unroll
  for (int ti = 0; ti < 4; ++ti) {
#pragma unroll
    for (int i = 0; i < 4; ++i) {
      float b1 = INFINITY, b2 = INFINITY; int i1 = 0;
#pragma unroll
      for (int j = 0; j < 4; ++j) {                // j ascending = m ascending
        float s = tq[j] - 2.0f * acc[ti][j][i];
        if (s < b1) { b2 = b1; b1 = s; i1 = mbase[j]; }
        else b2 = fminf(b2, s);
      }
#pragma unroll
      for (int mask = 1; mask <= 8; mask <<= 1) {  // reduce over 16 r-lanes
        float ob = __shfl_xor(b1, mask), os = __shfl_xor(b2, mask);
        int oi = __shfl_xor(i1, mask);
        float hi = fmaxf(b1, ob);
        if (ob < b1 || (ob == b1 && oi < i1)) { b1 = ob; i1 = oi; }
        b2 = fminf(fminf(b2, os), hi);
      }
      if (r == 0) {
        int token = tokb * 128 + ((w >> 1) * 4 + ti) * 16 + q * 4 + i;
        bestc  [(size_t)chunk * N_TOK + token] = b1;
        secondc[(size_t)chunk * N_TOK + token] = b2;
        idxc   [(size_t)chunk * N_TOK + token] = i1;
      }
    }
  }
}

// ---------- kernel 3: 32-way merge, flag, compacted worklist ----------
__global__ void merge_kernel(const float* __restrict__ bestc, const float* __restrict__ secondc,
                             const int* __restrict__ idxc, int* __restrict__ bestIdx,
                             int* __restrict__ flag, int* __restrict__ work,
                             int* __restrict__ wcount) {
  int t = blockIdx.x * blockDim.x + threadIdx.x;
  if (t >= N_TOK) return;
  float b1 = INFINITY, b2 = INFINITY; int i1 = 0x7fffffff; bool anyNan = false;
  for (int c = 0; c < NCHUNK; ++c) {
    float bc = bestc[(size_t)c * N_TOK + t], sc = secondc[(size_t)c * N_TOK + t];
    int ic = idxc[(size_t)c * N_TOK + t];
    anyNan = anyNan || (bc != bc) || (sc != sc);
    if (bc < b1 || (bc == b1 && ic < i1)) { b2 = fminf(fminf(b2, b1), sc); b1 = bc; i1 = ic; }
    else b2 = fminf(b2, fminf(bc, sc));
  }
  bestIdx[t] = i1;
  bool ok = (b2 - b1 >= CWIN) && (i1 >= 0) && (i1 < NEMB) && !anyNan && (b1 == b1);
  flag[t] = ok ? 0 : 1;
  if (!ok) {
    float limit = b1 + CWIN;
    for (int c = 0; c < NCHUNK; ++c) {
      float bc = bestc[(size_t)c * N_TOK + t];
      if (anyNan || !(bc > limit)) {               // NaN-safe candidate test
        int pos = atomicAdd(wcount, 1);
        if (pos < WCAP) work[pos] = t * NCHUNK + c;
      }
    }
  }
}

// ---------- kernel 4: coalesced f32-emulated rescan over worklist pairs ----------
__global__ __launch_bounds__(256) void refine_kernel(
    const float* __restrict__ enc, const float* __restrict__ tmp,
    const float* __restrict__ esq, const float* __restrict__ tsq,
    const int* __restrict__ work, const int* __restrict__ wcount,
    unsigned long long* __restrict__ rkey) {
  int total = *wcount; if (total > WCAP) total = WCAP;
  __shared__ float se[EMB];
  const int wv = threadIdx.x >> 6, lane = threadIdx.x & 63;
  for (int p = blockIdx.x; p < total; p += gridDim.x) {
    __syncthreads();
    int item = work[p];
    int token = item / NCHUNK, c = item % NCHUNK;
    const float4* erow = (const float4*)(enc + (size_t)token * EMB);
    for (int i = threadIdx.x; i < 128; i += 256) ((float4*)se)[i] = erow[i];
    __syncthreads();
    float e2 = esq[token];
    unsigned long long lkey = ~0ULL;
#pragma unroll
    for (int j = 0; j < 16; ++j) {
      int m = c * 64 + wv + j * 4;
      const float4* trow = (const float4*)(tmp + (size_t)m * EMB);
      float4 a0 = trow[lane], a1 = trow[lane + 64];
      float4 b0 = ((const float4*)se)[lane], b1 = ((const float4*)se)[lane + 64];
      double s = (double)a0.x * b0.x + (double)a0.y * b0.y
               + (double)a0.z * b0.z + (double)a0.w * b0.w
               + (double)a1.x * b1.x + (double)a1.y * b1.y
               + (double)a1.z * b1.z + (double)a1.w * b1.w;
#pragma unroll
      for (int mask = 1; mask < 64; mask <<= 1) s += __shfl_xor(s, mask);
      if (lane == 0) {
        float M  = (float)s;
        float d1 = __fadd_rn(e2, -__fmul_rn(2.0f, M));
        float d2 = __fadd_rn(d1, tsq[m]);
        unsigned long long key =
            ((unsigned long long)__float_as_uint(d2) << 32) | (unsigned)m;
        if (key < lkey) lkey = key;
      }
    }
    if (lane == 0 && lkey != ~0ULL) atomicMin(&rkey[token], lkey);
  }
}

// ---------- kernel 5: gather f32 rows + zidx as f32 ----------
__global__ void gather_kernel(const float* __restrict__ tmp, const int* __restrict__ bestIdx,
                              const int* __restrict__ flag,
                              const unsigned long long* __restrict__ rkey,
                              float* __restrict__ out) {
  int token = blockIdx.x * 4 + (threadIdx.x >> 6);
  int lane = threadIdx.x & 63;
  int idx = flag[token] ? (int)(unsigned)(rkey[token] & 0xffffffffULL) : bestIdx[token];
  idx = idx < 0 ? 0 : (idx > NEMB - 1 ? NEMB - 1 : idx);
  const float4* src = (const float4*)(tmp + (size_t)idx * EMB) + lane * 2;
  float4* dst = (float4*)(out + (size_t)token * EMB) + lane * 2;
  dst[0] = src[0];
  dst[1] = src[1];
  if (lane == 0) out[(size_t)N_TOK * EMB + token] = (float)idx;
}

extern "C" void kernel_launch(void* const* d_in, const int* in_sizes, int n_in,
                              void* d_out, int out_size, void* d_ws, size_t ws_size,
                              hipStream_t stream) {
  const float* enc = (const float*)d_in[0];
  const float* tmp = (const float*)d_in[1];
  float* out = (float*)d_out;
  char* ws = (char*)d_ws;
  unsigned short* thi = (unsigned short*)ws;                 //  2,097,152 B
  float* tsq      = (float*)(ws + 2097152);                  //      8,192 B
  float* esq      = (float*)(ws + 2105344);                  //     65,536 B
  float* bestc    = (float*)(ws + 2170880);                  //  2,097,152 B
  float* secondc  = (float*)(ws + 4268032);                  //  2,097,152 B
  int*   idxc     = (int*)  (ws + 6365184);                  //  2,097,152 B
  int*   bestIdx  = (int*)  (ws + 8462336);                  //     65,536 B
  int*   flag     = (int*)  (ws + 8527872);                  //     65,536 B
  unsigned long long* rkey = (unsigned long long*)(ws + 8593408); // 131,072 B
  int*   wcount   = (int*)  (ws + 8724480);                  //         64 B
  int*   work     = (int*)  (ws + 8724544);                  //  2,097,152 B

  hipMemsetAsync(wcount, 0,    64,     stream);
  hipMemsetAsync(rkey,   0xFF, 131072, stream);

  prep_t_kernel<<<NEMB,      64,  0, stream>>>(tmp, thi, tsq);
  esq_kernel   <<<N_TOK/4,   256, 0, stream>>>(enc, esq);
  score_kernel <<<2048,      256, 0, stream>>>(enc, thi, tsq, bestc, secondc, idxc);
  merge_kernel <<<N_TOK/256, 256, 0, stream>>>(bestc, secondc, idxc, bestIdx,
                                               flag, work, wcount);
  refine_kernel<<<1024,      256, 0, stream>>>(enc, tmp, esq, tsq, work, wcount, rkey);
  gather_kernel<<<N_TOK/4,   256, 0, stream>>>(tmp, bestIdx, flag, rkey, out);
}

// Round 7
// 252.995 us; speedup vs baseline: 1.1486x; 1.1486x over previous
//
#include <hip/hip_runtime.h>
#include <stdint.h>

#define N_TOK  16384
#define EMB    512
#define NEMB   2048
#define NCHUNK 32            // 64 templates per chunk
#define CWIN   2.5e-4f       // ref-f32-grid + bf16 score-noise margin (passed R5/R6)
#define WCAP   524288

typedef __attribute__((ext_vector_type(8))) short s16x8;
typedef __attribute__((ext_vector_type(4))) float f32x4;

__device__ __forceinline__ unsigned short f2bf(float f) {   // RNE f32 -> bf16
  unsigned u = __float_as_uint(f);
  u += 0x7fffu + ((u >> 16) & 1u);
  return (unsigned short)(u >> 16);
}

// numpy pairwise_sum emulation for sum(x*x) over 512 contiguous f32.
__device__ __forceinline__ float pairwise512_sq(const float* se, int lane) {
  int l = lane & 31;
  int b = l >> 3, j = l & 7;
  const float* base = se + b * 128 + j;
  float x = base[0];
  float r = __fmul_rn(x, x);
#pragma unroll
  for (int k = 1; k < 16; ++k) {
    float y = base[8 * k];
    r = __fadd_rn(r, __fmul_rn(y, y));
  }
  r = __fadd_rn(r, __shfl_xor(r, 1));
  r = __fadd_rn(r, __shfl_xor(r, 2));
  r = __fadd_rn(r, __shfl_xor(r, 4));
  r = __fadd_rn(r, __shfl_xor(r, 8));
  r = __fadd_rn(r, __shfl_xor(r, 16));
  return r;
}

// ---------- kernel 1 (fused prep): rows 0..2047 = templat -> thi+tsq,
//            rows 2048.. = encode -> ehi+esq. Also zeroes wcount. ----------
__global__ void prep_kernel(const float* __restrict__ tmp, const float* __restrict__ enc,
                            unsigned short* __restrict__ thi, float* __restrict__ tsq,
                            unsigned short* __restrict__ ehi, float* __restrict__ esq,
                            int* __restrict__ wcount) {
  __shared__ float se[EMB];
  int row = blockIdx.x, lane = threadIdx.x;                  // 64 lanes
  if (row == 0 && lane == 0) *wcount = 0;
  bool isT = row < NEMB;
  const float* src = isT ? (tmp + (size_t)row * EMB)
                         : (enc + (size_t)(row - NEMB) * EMB);
  const float4* p = (const float4*)src + lane * 2;
  float4 v0 = p[0], v1 = p[1];
  float f[8] = {v0.x, v0.y, v0.z, v0.w, v1.x, v1.y, v1.z, v1.w};
  unsigned h[8];
#pragma unroll
  for (int i = 0; i < 8; ++i) { h[i] = f2bf(f[i]); se[lane * 8 + i] = f[i]; }
  uint4 packed = { h[0] | (h[1] << 16), h[2] | (h[3] << 16),
                   h[4] | (h[5] << 16), h[6] | (h[7] << 16) };
  unsigned short* dsth = isT ? (thi + (size_t)row * EMB)
                             : (ehi + (size_t)(row - NEMB) * EMB);
  ((uint4*)dsth)[lane] = packed;
  __syncthreads();
  float s = pairwise512_sq(se, lane);
  if (lane == 0) { if (isT) tsq[row] = s; else esq[row - NEMB] = s; }
}

// ---------- kernel 2: m97-structure GEMM (bf16 A and B via global_load_lds)
//            + fused per-(token,chunk) argmin epilogue ----------
// grid 2048: tokb = bid>>4 (128 tokens), mb = bid&15 (128 templates). BK=64.
// Wave w: token-tiles (w>>1)*4+{0..3}, m-tiles (w&1)*4+{0..3} -> 64x64 output.
__global__ __launch_bounds__(256, 3) void score_kernel(
    const unsigned short* __restrict__ ehi, const unsigned short* __restrict__ thi,
    const float* __restrict__ tsq,
    float* __restrict__ bestc, float* __restrict__ secondc, int* __restrict__ idxc) {
  __shared__ uint4 sA[1024];                    // 16 KB: [(tile*2+ks)*64 + lane]
  __shared__ uint4 sB[1024];                    // 16 KB
  const int tid = threadIdx.x, w = tid >> 6, lane = tid & 63;
  const int q = lane >> 4, r = lane & 15;
  const int tokb = (int)blockIdx.x >> 4;
  const int mb   = (int)blockIdx.x & 15;

  f32x4 acc[4][4];
#pragma unroll
  for (int ti = 0; ti < 4; ++ti)
#pragma unroll
    for (int j = 0; j < 4; ++j) acc[ti][j] = (f32x4){0.f, 0.f, 0.f, 0.f};

  for (int kb = 0; kb < 8; ++kb) {
    const int colb = kb * 64;
    // stage A (4 wave-loads) and B (4 wave-loads), fragment order
#pragma unroll
    for (int n = 0; n < 4; ++n) {
      int p = w + n * 4, tile = p >> 1, ks = p & 1;
      const unsigned short* ga =
          ehi + (size_t)(tokb * 128 + tile * 16 + r) * EMB + colb + ks * 32 + q * 8;
      __builtin_amdgcn_global_load_lds(
          (const __attribute__((address_space(1))) void*)ga,
          (__attribute__((address_space(3))) void*)&sA[(tile * 2 + ks) * 64], 16, 0, 0);
      const unsigned short* gb =
          thi + (size_t)(mb * 128 + tile * 16 + r) * EMB + colb + ks * 32 + q * 8;
      __builtin_amdgcn_global_load_lds(
          (const __attribute__((address_space(1))) void*)gb,
          (__attribute__((address_space(3))) void*)&sB[(tile * 2 + ks) * 64], 16, 0, 0);
    }
    __syncthreads();
#pragma unroll
    for (int ks = 0; ks < 2; ++ks) {
      s16x8 af[4], bfr[4];
#pragma unroll
      for (int ti = 0; ti < 4; ++ti)
        af[ti] = ((const s16x8*)sA)[((((w >> 1) * 4 + ti) * 2 + ks) << 6) + lane];
#pragma unroll
      for (int j = 0; j < 4; ++j)
        bfr[j] = ((const s16x8*)sB)[((((w & 1) * 4 + j) * 2 + ks) << 6) + lane];
#pragma unroll
      for (int ti = 0; ti < 4; ++ti)
#pragma unroll
        for (int j = 0; j < 4; ++j)
          acc[ti][j] = __builtin_amdgcn_mfma_f32_16x16x32_bf16(af[ti], bfr[j],
                                                               acc[ti][j], 0, 0, 0);
    }
    __syncthreads();
  }

  // ---- epilogue: per-(token,chunk) best/second/idx ----
  // C/D layout: col(template) = r, row(token) = q*4 + i
  const int chunk = mb * 2 + (w & 1);
  float tq[4]; int mbase[4];
#pragma unroll
  for (int j = 0; j < 4; ++j) {
    mbase[j] = mb * 128 + ((w & 1) * 4 + j) * 16 + r;
    tq[j] = tsq[mbase[j]];
  }
#pragma unroll
  for (int ti = 0; ti < 4; ++ti) {
#pragma unroll
    for (int i = 0; i < 4; ++i) {
      float b1 = INFINITY, b2 = INFINITY; int i1 = 0;
#pragma unroll
      for (int j = 0; j < 4; ++j) {                // j ascending = m ascending
        float s = tq[j] - 2.0f * acc[ti][j][i];
        if (s < b1) { b2 = b1; b1 = s; i1 = mbase[j]; }
        else b2 = fminf(b2, s);
      }
#pragma unroll
      for (int mask = 1; mask <= 8; mask <<= 1) {  // reduce over 16 r-lanes
        float ob = __shfl_xor(b1, mask), os = __shfl_xor(b2, mask);
        int oi = __shfl_xor(i1, mask);
        float hi = fmaxf(b1, ob);
        if (ob < b1 || (ob == b1 && oi < i1)) { b1 = ob; i1 = oi; }
        b2 = fminf(fminf(b2, os), hi);
      }
      if (r == 0) {
        int token = tokb * 128 + ((w >> 1) * 4 + ti) * 16 + q * 4 + i;
        bestc  [(size_t)chunk * N_TOK + token] = b1;
        secondc[(size_t)chunk * N_TOK + token] = b2;
        idxc   [(size_t)chunk * N_TOK + token] = i1;
      }
    }
  }
}

// ---------- kernel 3: 32-way merge, flag, worklist; inits rkey ----------
__global__ void merge_kernel(const float* __restrict__ bestc, const float* __restrict__ secondc,
                             const int* __restrict__ idxc, int* __restrict__ bestIdx,
                             int* __restrict__ flag, int* __restrict__ work,
                             int* __restrict__ wcount, unsigned long long* __restrict__ rkey) {
  int t = blockIdx.x * blockDim.x + threadIdx.x;
  if (t >= N_TOK) return;
  rkey[t] = ~0ULL;
  float b1 = INFINITY, b2 = INFINITY; int i1 = 0x7fffffff; bool anyNan = false;
  for (int c = 0; c < NCHUNK; ++c) {
    float bc = bestc[(size_t)c * N_TOK + t], sc = secondc[(size_t)c * N_TOK + t];
    int ic = idxc[(size_t)c * N_TOK + t];
    anyNan = anyNan || (bc != bc) || (sc != sc);
    if (bc < b1 || (bc == b1 && ic < i1)) { b2 = fminf(fminf(b2, b1), sc); b1 = bc; i1 = ic; }
    else b2 = fminf(b2, fminf(bc, sc));
  }
  bestIdx[t] = i1;
  bool ok = (b2 - b1 >= CWIN) && (i1 >= 0) && (i1 < NEMB) && !anyNan && (b1 == b1);
  flag[t] = ok ? 0 : 1;
  if (!ok) {
    float limit = b1 + CWIN;
    for (int c = 0; c < NCHUNK; ++c) {
      float bc = bestc[(size_t)c * N_TOK + t];
      if (anyNan || !(bc > limit)) {               // NaN-safe candidate test
        int pos = atomicAdd(wcount, 1);
        if (pos < WCAP) work[pos] = t * NCHUNK + c;
      }
    }
  }
}

// ---------- kernel 4: coalesced f32-emulated rescan over worklist pairs ----------
__global__ __launch_bounds__(256) void refine_kernel(
    const float* __restrict__ enc, const float* __restrict__ tmp,
    const float* __restrict__ esq, const float* __restrict__ tsq,
    const int* __restrict__ work, const int* __restrict__ wcount,
    unsigned long long* __restrict__ rkey) {
  int total = *wcount; if (total > WCAP) total = WCAP;
  __shared__ float se[EMB];
  const int wv = threadIdx.x >> 6, lane = threadIdx.x & 63;
  for (int p = blockIdx.x; p < total; p += gridDim.x) {
    __syncthreads();
    int item = work[p];
    int token = item / NCHUNK, c = item % NCHUNK;
    const float4* erow = (const float4*)(enc + (size_t)token * EMB);
    for (int i = threadIdx.x; i < 128; i += 256) ((float4*)se)[i] = erow[i];
    __syncthreads();
    float e2 = esq[token];
    unsigned long long lkey = ~0ULL;
#pragma unroll
    for (int j = 0; j < 16; ++j) {
      int m = c * 64 + wv + j * 4;
      const float4* trow = (const float4*)(tmp + (size_t)m * EMB);
      float4 a0 = trow[lane], a1 = trow[lane + 64];
      float4 b0 = ((const float4*)se)[lane], b1 = ((const float4*)se)[lane + 64];
      double s = (double)a0.x * b0.x + (double)a0.y * b0.y
               + (double)a0.z * b0.z + (double)a0.w * b0.w
               + (double)a1.x * b1.x + (double)a1.y * b1.y
               + (double)a1.z * b1.z + (double)a1.w * b1.w;
#pragma unroll
      for (int mask = 1; mask < 64; mask <<= 1) s += __shfl_xor(s, mask);
      if (lane == 0) {
        float M  = (float)s;
        float d1 = __fadd_rn(e2, -__fmul_rn(2.0f, M));
        float d2 = __fadd_rn(d1, tsq[m]);
        unsigned long long key =
            ((unsigned long long)__float_as_uint(d2) << 32) | (unsigned)m;
        if (key < lkey) lkey = key;
      }
    }
    if (lane == 0 && lkey != ~0ULL) atomicMin(&rkey[token], lkey);
  }
}

// ---------- kernel 5: gather f32 rows + zidx as f32 ----------
__global__ void gather_kernel(const float* __restrict__ tmp, const int* __restrict__ bestIdx,
                              const int* __restrict__ flag,
                              const unsigned long long* __restrict__ rkey,
                              float* __restrict__ out) {
  int token = blockIdx.x * 4 + (threadIdx.x >> 6);
  int lane = threadIdx.x & 63;
  int idx = flag[token] ? (int)(unsigned)(rkey[token] & 0xffffffffULL) : bestIdx[token];
  idx = idx < 0 ? 0 : (idx > NEMB - 1 ? NEMB - 1 : idx);
  const float4* src = (const float4*)(tmp + (size_t)idx * EMB) + lane * 2;
  float4* dst = (float4*)(out + (size_t)token * EMB) + lane * 2;
  dst[0] = src[0];
  dst[1] = src[1];
  if (lane == 0) out[(size_t)N_TOK * EMB + token] = (float)idx;
}

extern "C" void kernel_launch(void* const* d_in, const int* in_sizes, int n_in,
                              void* d_out, int out_size, void* d_ws, size_t ws_size,
                              hipStream_t stream) {
  const float* enc = (const float*)d_in[0];
  const float* tmp = (const float*)d_in[1];
  float* out = (float*)d_out;
  char* ws = (char*)d_ws;
  unsigned short* thi = (unsigned short*)ws;                 //  2,097,152 B
  unsigned short* ehi = (unsigned short*)(ws + 2097152);     // 16,777,216 B
  float* tsq      = (float*)(ws + 18874368);                 //      8,192 B
  float* esq      = (float*)(ws + 18882560);                 //     65,536 B
  float* bestc    = (float*)(ws + 18948096);                 //  2,097,152 B
  float* secondc  = (float*)(ws + 21045248);                 //  2,097,152 B
  int*   idxc     = (int*)  (ws + 23142400);                 //  2,097,152 B
  int*   bestIdx  = (int*)  (ws + 25239552);                 //     65,536 B
  int*   flag     = (int*)  (ws + 25305088);                 //     65,536 B
  unsigned long long* rkey = (unsigned long long*)(ws + 25370624); // 131,072 B
  int*   wcount   = (int*)  (ws + 25501696);                 //         64 B
  int*   work     = (int*)  (ws + 25501760);                 //  2,097,152 B

  prep_kernel  <<<NEMB + N_TOK, 64, 0, stream>>>(tmp, enc, thi, tsq, ehi, esq, wcount);
  score_kernel <<<2048,      256, 0, stream>>>(ehi, thi, tsq, bestc, secondc, idxc);
  merge_kernel <<<N_TOK/256, 256, 0, stream>>>(bestc, secondc, idxc, bestIdx,
                                               flag, work, wcount, rkey);
  refine_kernel<<<1024,      256, 0, stream>>>(enc, tmp, esq, tsq, work, wcount, rkey);
  gather_kernel<<<N_TOK/4,   256, 0, stream>>>(tmp, bestIdx, flag, rkey, out);
}

// Round 8
// 225.330 us; speedup vs baseline: 1.2896x; 1.1228x over previous
//
#include <hip/hip_runtime.h>
#include <stdint.h>

#define N_TOK  16384
#define EMB    512
#define NEMB   2048
#define NCHUNK 32            // 64 templates per chunk
#define CWIN   2.5e-4f       // ref-f32-grid + bf16 score-noise margin (passed R5-R7)
#define WCAP   524288
#define EPAD   19            // LDS row stride (u64/u32 units) for epilogue transpose

typedef __attribute__((ext_vector_type(8))) short s16x8;
typedef __attribute__((ext_vector_type(4))) float f32x4;

__device__ __forceinline__ unsigned short f2bf(float f) {   // RNE f32 -> bf16
  unsigned u = __float_as_uint(f);
  u += 0x7fffu + ((u >> 16) & 1u);
  return (unsigned short)(u >> 16);
}
// monotone f32 -> u32 (total order, NaN sorts above all reals)
__device__ __forceinline__ unsigned mapf(float f) {
  unsigned u = __float_as_uint(f);
  return (u >> 31) ? ~u : (u | 0x80000000u);
}
__device__ __forceinline__ float unmapf(unsigned u) {
  return __uint_as_float((u >> 31) ? (u & 0x7fffffffu) : ~u);
}

// numpy pairwise_sum emulation for sum(x*x) over 512 contiguous f32.
__device__ __forceinline__ float pairwise512_sq(const float* se, int lane) {
  int l = lane & 31;
  int b = l >> 3, j = l & 7;
  const float* base = se + b * 128 + j;
  float x = base[0];
  float r = __fmul_rn(x, x);
#pragma unroll
  for (int k = 1; k < 16; ++k) {
    float y = base[8 * k];
    r = __fadd_rn(r, __fmul_rn(y, y));
  }
  r = __fadd_rn(r, __shfl_xor(r, 1));
  r = __fadd_rn(r, __shfl_xor(r, 2));
  r = __fadd_rn(r, __shfl_xor(r, 4));
  r = __fadd_rn(r, __shfl_xor(r, 8));
  r = __fadd_rn(r, __shfl_xor(r, 16));
  return r;
}

// ---------- kernel 1: fused prep, 4 rows per block (wave per row) ----------
__global__ __launch_bounds__(256) void prep_kernel(
    const float* __restrict__ tmp, const float* __restrict__ enc,
    unsigned short* __restrict__ thi, float* __restrict__ tsq,
    unsigned short* __restrict__ ehi, float* __restrict__ esq,
    int* __restrict__ wcount) {
  __shared__ float se[4][EMB];
  int wv = threadIdx.x >> 6, lane = threadIdx.x & 63;
  int row = blockIdx.x * 4 + wv;                             // 18432 rows
  if (blockIdx.x == 0 && threadIdx.x == 0) *wcount = 0;
  bool isT = row < NEMB;
  const float* src = isT ? (tmp + (size_t)row * EMB)
                         : (enc + (size_t)(row - NEMB) * EMB);
  const float4* p = (const float4*)src + lane * 2;
  float4 v0 = p[0], v1 = p[1];
  float f[8] = {v0.x, v0.y, v0.z, v0.w, v1.x, v1.y, v1.z, v1.w};
  unsigned h[8];
#pragma unroll
  for (int i = 0; i < 8; ++i) { h[i] = f2bf(f[i]); se[wv][lane * 8 + i] = f[i]; }
  uint4 packed = { h[0] | (h[1] << 16), h[2] | (h[3] << 16),
                   h[4] | (h[5] << 16), h[6] | (h[7] << 16) };
  unsigned short* dsth = isT ? (thi + (size_t)row * EMB)
                             : (ehi + (size_t)(row - NEMB) * EMB);
  ((uint4*)dsth)[lane] = packed;
  __syncthreads();
  float s = pairwise512_sq(se[wv], lane);
  if (lane == 0) { if (isT) tsq[row] = s; else esq[row - NEMB] = s; }
}

// ---------- kernel 2: m97-structure GEMM + LDS-transpose argmin epilogue ----------
// grid 2048: tokb = bid>>4 (128 tokens), mb = bid&15 (128 templates). BK=64.
__global__ __launch_bounds__(256, 3) void score_kernel(
    const unsigned short* __restrict__ ehi, const unsigned short* __restrict__ thi,
    const float* __restrict__ tsq,
    unsigned long long* __restrict__ keyc, unsigned* __restrict__ s2c) {
  __shared__ __align__(16) char smem[32768];
  uint4* sA = (uint4*)smem;                     // 16 KB
  uint4* sB = (uint4*)(smem + 16384);           // 16 KB
  const int tid = threadIdx.x, w = tid >> 6, lane = tid & 63;
  const int q = lane >> 4, r = lane & 15;
  const int tokb = (int)blockIdx.x >> 4;
  const int mb   = (int)blockIdx.x & 15;

  f32x4 acc[4][4];
#pragma unroll
  for (int ti = 0; ti < 4; ++ti)
#pragma unroll
    for (int j = 0; j < 4; ++j) acc[ti][j] = (f32x4){0.f, 0.f, 0.f, 0.f};

  for (int kb = 0; kb < 8; ++kb) {
    const int colb = kb * 64;
#pragma unroll
    for (int n = 0; n < 4; ++n) {
      int p = w + n * 4, tile = p >> 1, ks = p & 1;
      const unsigned short* ga =
          ehi + (size_t)(tokb * 128 + tile * 16 + r) * EMB + colb + ks * 32 + q * 8;
      __builtin_amdgcn_global_load_lds(
          (const __attribute__((address_space(1))) void*)ga,
          (__attribute__((address_space(3))) void*)&sA[(tile * 2 + ks) * 64], 16, 0, 0);
      const unsigned short* gb =
          thi + (size_t)(mb * 128 + tile * 16 + r) * EMB + colb + ks * 32 + q * 8;
      __builtin_amdgcn_global_load_lds(
          (const __attribute__((address_space(1))) void*)gb,
          (__attribute__((address_space(3))) void*)&sB[(tile * 2 + ks) * 64], 16, 0, 0);
    }
    __syncthreads();
#pragma unroll
    for (int ks = 0; ks < 2; ++ks) {
      s16x8 af[4], bfr[4];
#pragma unroll
      for (int ti = 0; ti < 4; ++ti)
        af[ti] = ((const s16x8*)sA)[((((w >> 1) * 4 + ti) * 2 + ks) << 6) + lane];
#pragma unroll
      for (int j = 0; j < 4; ++j)
        bfr[j] = ((const s16x8*)sB)[((((w & 1) * 4 + j) * 2 + ks) << 6) + lane];
#pragma unroll
      for (int ti = 0; ti < 4; ++ti)
#pragma unroll
        for (int j = 0; j < 4; ++j)
          acc[ti][j] = __builtin_amdgcn_mfma_f32_16x16x32_bf16(af[ti], bfr[j],
                                                               acc[ti][j], 0, 0, 0);
    }
    __syncthreads();
  }

  // ---- epilogue v2: two-phase LDS transpose; chunk = mb*2 + (w&1) ----
  unsigned long long* K1 = (unsigned long long*)smem;        // 128*EPAD u64 = 19456 B
  unsigned* S2 = (unsigned*)(smem + 128 * EPAD * 8);         // 128*EPAD u32 =  9728 B
  float tq[4]; int mbase[4];
#pragma unroll
  for (int j = 0; j < 4; ++j) {
    mbase[j] = mb * 128 + ((w & 1) * 4 + j) * 16 + r;
    tq[j] = tsq[mbase[j]];
  }
#pragma unroll
  for (int phase = 0; phase < 2; ++phase) {
    if ((w & 1) == phase) {
#pragma unroll
      for (int ti = 0; ti < 4; ++ti) {
#pragma unroll
        for (int i = 0; i < 4; ++i) {
          unsigned long long k1 = ~0ULL; unsigned s2m = 0xffffffffu;
#pragma unroll
          for (int j = 0; j < 4; ++j) {              // j ascending = m ascending
            float s = tq[j] - 2.0f * acc[ti][j][i];
            unsigned sm = mapf(s);
            unsigned long long k = ((unsigned long long)sm << 32) | (unsigned)mbase[j];
            if (k < k1) { unsigned o = (unsigned)(k1 >> 32); s2m = o < s2m ? o : s2m; k1 = k; }
            else s2m = sm < s2m ? sm : s2m;
          }
          int tl = (w >> 1) * 64 + ti * 16 + q * 4 + i;
          K1[tl * EPAD + r] = k1;
          S2[tl * EPAD + r] = s2m;
        }
      }
    }
    __syncthreads();
    if (tid < 128) {
      int tl = tid;
      unsigned long long K = ~0ULL; unsigned S = 0xffffffffu;
#pragma unroll
      for (int rr = 0; rr < 16; ++rr) {
        unsigned long long k = K1[tl * EPAD + rr];
        unsigned s2 = S2[tl * EPAD + rr];
        if (k < K) { unsigned o = (unsigned)(K >> 32); S = o < S ? o : S; K = k; }
        else { unsigned o = (unsigned)(k >> 32); S = o < S ? o : S; }
        S = s2 < S ? s2 : S;
      }
      int token = tokb * 128 + tl;
      int chunk = mb * 2 + phase;
      keyc[(size_t)chunk * N_TOK + token] = K;
      s2c [(size_t)chunk * N_TOK + token] = S;
    }
    __syncthreads();
  }
}

// ---------- kernel 3: 32-way key merge, flag, worklist; inits rkey ----------
__global__ __launch_bounds__(64) void merge_kernel(
    const unsigned long long* __restrict__ keyc, const unsigned* __restrict__ s2c,
    int* __restrict__ bestIdx, int* __restrict__ flag, int* __restrict__ work,
    int* __restrict__ wcount, unsigned long long* __restrict__ rkey) {
  int t = blockIdx.x * 64 + threadIdx.x;
  if (t >= N_TOK) return;
  rkey[t] = ~0ULL;
  unsigned long long K = ~0ULL; unsigned S = 0xffffffffu;
  for (int c = 0; c < NCHUNK; ++c) {
    unsigned long long k = keyc[(size_t)c * N_TOK + t];
    unsigned s2 = s2c[(size_t)c * N_TOK + t];
    if (k < K) { unsigned o = (unsigned)(K >> 32); S = o < S ? o : S; K = k; }
    else { unsigned o = (unsigned)(k >> 32); S = o < S ? o : S; }
    S = s2 < S ? s2 : S;
  }
  float best_f   = unmapf((unsigned)(K >> 32));
  float second_f = unmapf(S);
  int idx = (int)(unsigned)(K & 0xffffffffu);
  bestIdx[t] = idx;
  bool ok = (second_f - best_f >= CWIN) && (idx >= 0) && (idx < NEMB) && (best_f == best_f);
  flag[t] = ok ? 0 : 1;
  if (!ok) {
    bool nanCase = !(best_f == best_f);
    float limit = best_f + CWIN;
    for (int c = 0; c < NCHUNK; ++c) {
      float cf = unmapf((unsigned)(keyc[(size_t)c * N_TOK + t] >> 32));
      if (nanCase || !(cf > limit)) {               // NaN-safe candidate test
        int pos = atomicAdd(wcount, 1);
        if (pos < WCAP) work[pos] = t * NCHUNK + c;
      }
    }
  }
}

// ---------- kernel 4: coalesced f32-emulated rescan over worklist pairs ----------
__global__ __launch_bounds__(256) void refine_kernel(
    const float* __restrict__ enc, const float* __restrict__ tmp,
    const float* __restrict__ esq, const float* __restrict__ tsq,
    const int* __restrict__ work, const int* __restrict__ wcount,
    unsigned long long* __restrict__ rkey) {
  int total = *wcount; if (total > WCAP) total = WCAP;
  __shared__ float se[EMB];
  const int wv = threadIdx.x >> 6, lane = threadIdx.x & 63;
  for (int p = blockIdx.x; p < total; p += gridDim.x) {
    __syncthreads();
    int item = work[p];
    int token = item / NCHUNK, c = item % NCHUNK;
    const float4* erow = (const float4*)(enc + (size_t)token * EMB);
    for (int i = threadIdx.x; i < 128; i += 256) ((float4*)se)[i] = erow[i];
    __syncthreads();
    float e2 = esq[token];
    unsigned long long lkey = ~0ULL;
#pragma unroll
    for (int j = 0; j < 16; ++j) {
      int m = c * 64 + wv + j * 4;
      const float4* trow = (const float4*)(tmp + (size_t)m * EMB);
      float4 a0 = trow[lane], a1 = trow[lane + 64];
      float4 b0 = ((const float4*)se)[lane], b1 = ((const float4*)se)[lane + 64];
      double s = (double)a0.x * b0.x + (double)a0.y * b0.y
               + (double)a0.z * b0.z + (double)a0.w * b0.w
               + (double)a1.x * b1.x + (double)a1.y * b1.y
               + (double)a1.z * b1.z + (double)a1.w * b1.w;
#pragma unroll
      for (int mask = 1; mask < 64; mask <<= 1) s += __shfl_xor(s, mask);
      if (lane == 0) {
        float M  = (float)s;
        float d1 = __fadd_rn(e2, -__fmul_rn(2.0f, M));
        float d2 = __fadd_rn(d1, tsq[m]);            // full dist >= 0: bits monotone
        unsigned long long key =
            ((unsigned long long)__float_as_uint(d2) << 32) | (unsigned)m;
        if (key < lkey) lkey = key;
      }
    }
    if (lane == 0 && lkey != ~0ULL) atomicMin(&rkey[token], lkey);
  }
}

// ---------- kernel 5: gather f32 rows + zidx as f32 ----------
__global__ void gather_kernel(const float* __restrict__ tmp, const int* __restrict__ bestIdx,
                              const int* __restrict__ flag,
                              const unsigned long long* __restrict__ rkey,
                              float* __restrict__ out) {
  int token = blockIdx.x * 4 + (threadIdx.x >> 6);
  int lane = threadIdx.x & 63;
  int idx = flag[token] ? (int)(unsigned)(rkey[token] & 0xffffffffULL) : bestIdx[token];
  idx = idx < 0 ? 0 : (idx > NEMB - 1 ? NEMB - 1 : idx);
  const float4* src = (const float4*)(tmp + (size_t)idx * EMB) + lane * 2;
  float4* dst = (float4*)(out + (size_t)token * EMB) + lane * 2;
  dst[0] = src[0];
  dst[1] = src[1];
  if (lane == 0) out[(size_t)N_TOK * EMB + token] = (float)idx;
}

extern "C" void kernel_launch(void* const* d_in, const int* in_sizes, int n_in,
                              void* d_out, int out_size, void* d_ws, size_t ws_size,
                              hipStream_t stream) {
  const float* enc = (const float*)d_in[0];
  const float* tmp = (const float*)d_in[1];
  float* out = (float*)d_out;
  char* ws = (char*)d_ws;
  unsigned short* thi = (unsigned short*)ws;                 //  2,097,152 B
  unsigned short* ehi = (unsigned short*)(ws + 2097152);     // 16,777,216 B
  float* tsq      = (float*)(ws + 18874368);                 //      8,192 B
  float* esq      = (float*)(ws + 18882560);                 //     65,536 B
  unsigned long long* keyc = (unsigned long long*)(ws + 18948096); // 4,194,304 B
  unsigned* s2c   = (unsigned*)(ws + 23142400);              //  2,097,152 B
  int*   bestIdx  = (int*)  (ws + 25239552);                 //     65,536 B
  int*   flag     = (int*)  (ws + 25305088);                 //     65,536 B
  unsigned long long* rkey = (unsigned long long*)(ws + 25370624); // 131,072 B
  int*   wcount   = (int*)  (ws + 25501696);                 //         64 B
  int*   work     = (int*)  (ws + 25501760);                 //  2,097,152 B

  prep_kernel  <<<4608,      256, 0, stream>>>(tmp, enc, thi, tsq, ehi, esq, wcount);
  score_kernel <<<2048,      256, 0, stream>>>(ehi, thi, tsq, keyc, s2c);
  merge_kernel <<<N_TOK/64,  64,  0, stream>>>(keyc, s2c, bestIdx, flag, work, wcount, rkey);
  refine_kernel<<<1024,      256, 0, stream>>>(enc, tmp, esq, tsq, work, wcount, rkey);
  gather_kernel<<<N_TOK/4,   256, 0, stream>>>(tmp, bestIdx, flag, rkey, out);
}